// Round 19
// baseline (398.994 us; speedup 1.0000x reference)
//
#include <hip/hip_runtime.h>

#define NE 64
#define TAU 1e-4f  // 4-term split-bf16 score sigma ~5e-6 -> 20-sigma guard
#define LSTR 68    // 68 mod 32 = 4 -> 2-way (free) LDS access in epilogue

typedef __bf16 bf16x8 __attribute__((ext_vector_type(8)));
typedef float f32x4 __attribute__((ext_vector_type(4)));

// split f32 -> bf16 hi + bf16 lo (hi RNE, lo = RNE(x - hi); x-hi exact in f32)
__device__ __forceinline__ void split8(const float4 a0, const float4 a1,
                                       bf16x8& hi, bf16x8& lo) {
  const float xs[8] = {a0.x, a0.y, a0.z, a0.w, a1.x, a1.y, a1.z, a1.w};
#pragma unroll
  for (int i = 0; i < 8; ++i) {
    const __bf16 h = (__bf16)xs[i];
    hi[i] = h;
    lo[i] = (__bf16)(xs[i] - (float)h);
  }
}

// async global->LDS, 16B/lane; LDS dest = wave-uniform base, HW adds lane*16
__device__ __forceinline__ void gld16(const void* g, void* l) {
  __builtin_amdgcn_global_load_lds(
      (const __attribute__((address_space(1))) void*)g,
      (__attribute__((address_space(3))) void*)l, 16, 0, 0);
}

// ---- Kernel Z: zero cnt+hist ------------------------------------------------
__global__ void zero512(int* __restrict__ p) { p[threadIdx.x] = 0; }

// ---- Kernel 0: W -> bf16 hi/lo in FRAGMENT-MAJOR 32-k tiles (1 MB, once) ---
// elem(tt, j, lk, lr, kr) = tt*2048 + j*512 + (lk*16+lr)*8 + kr
// where W-row e = 16j+lr, k = 32tt + 8lk + kr. A 256-k slice s = tt in
// [8s,8s+8) is 16384 contiguous elems (32 KB) -> linear DMA to LDS.
__global__ __launch_bounds__(256) void wconvert(const float* __restrict__ W,
                                                __bf16* __restrict__ Whi,
                                                __bf16* __restrict__ Wlo,
                                                int n8, int H) {
  const int i = blockIdx.x * 256 + threadIdx.x;
  if (i >= n8) return;
  const int hc = H >> 3;
  const int e = i / hc;
  const int k0 = (i - e * hc) * 8;
  const float4 a0 = *reinterpret_cast<const float4*>(W + (size_t)e * H + k0);
  const float4 a1 =
      *reinterpret_cast<const float4*>(W + (size_t)e * H + k0 + 4);
  bf16x8 hi, lo;
  split8(a0, a1, hi, lo);
  const int tt = k0 >> 5, lk = (k0 >> 3) & 3, j = e >> 4, lr = e & 15;
  const size_t off = (size_t)tt * 2048 + j * 512 + (lk * 16 + lr) * 8;
  *reinterpret_cast<bf16x8*>(Whi + off) = hi;
  *reinterpret_cast<bf16x8*>(Wlo + off) = lo;
}

// ------- Kernel 1: 1KB-grain-A GEMM (BK=256, B+A single-buffer LDS) ---------
// 4 waves x 16 tokens = 64 tokens/block; grid N/64 = 512 (1 block/CU, 128 KB
// LDS). Per 256-k slice per wave: 16 A gld16 (EACH = one token row's 1 KB,
// fully contiguous; 16B chunks XOR-preswizzled within the row) + 16 B gld16
// (fragment-major, 1 KB contiguous each); vmcnt(0); barrier; 8 barrier-free
// 32-k sub-steps (2 A + 8 B ds_read_b128, 16 MFMA 4-term split-bf16).
// All staging instructions are 64-lane x 16 B CONTIGUOUS -> m97-class rate.
__global__ __launch_bounds__(256) void gemm_fused(
    const float* __restrict__ X, const __bf16* __restrict__ Whi,
    const __bf16* __restrict__ Wlo, const float* __restrict__ bias,
    float* __restrict__ S, float* __restrict__ wout, float* __restrict__ iout,
    int* __restrict__ cnt, int* __restrict__ hist, int* __restrict__ list,
    int cap, int H, int K) {
  __shared__ alignas(16) char smem[131072];  // A 64K | BH 32K | BL 32K
  __shared__ int hist_s[NE];
  const int tid = threadIdx.x;
  const int lane = tid & 63;
  const int wave = tid >> 6;  // 0..3
  if (tid < NE) hist_s[tid] = 0;
  const int lr = lane & 15;
  const int lk = lane >> 4;
  const int row0 = blockIdx.x * 64;

  float* A0 = (float*)smem;              // [wave][16 rows][256 floats, swz]
  __bf16* BH = (__bf16*)(smem + 65536);  // [8 st][4 j][64 lane][8]
  __bf16* BL = (__bf16*)(smem + 98304);

  // A sources: one instr per row r; lane j covers 16B chunk j of the row's
  // 1 KB slice-run, holding LOGICAL chunk 8*(j>>3) + ((j&7) ^ (r&7)).
  const int w8 = (lane >> 3) << 3;
  const int u = lane & 7;
  const float* srcA[16];
#pragma unroll
  for (int r = 0; r < 16; ++r)
    srcA[r] =
        X + (size_t)(row0 + 16 * wave + r) * H + ((w8 + (u ^ (r & 7))) << 2);
  const __bf16* srcBh = Whi + wave * 4096 + lane * 8;
  const __bf16* srcBl = Wlo + wave * 4096 + lane * 8;

  f32x4 acc[4] = {};
  const int NSL = H >> 8;  // 16 slices of 256 k

  for (int s = 0; s < NSL; ++s) {
    if (s) __syncthreads();  // all waves done reading previous slice
    // ---- stage slice s: A 16 KB/wave + B 16 KB/wave, all 1KB-contiguous ----
#pragma unroll
    for (int r = 0; r < 16; ++r)
      gld16(srcA[r] + s * 256, A0 + wave * 4096 + r * 256);
#pragma unroll
    for (int i = 0; i < 8; ++i) {
      gld16(srcBh + (size_t)s * 16384 + i * 512, BH + wave * 4096 + i * 512);
      gld16(srcBl + (size_t)s * 16384 + i * 512, BL + wave * 4096 + i * 512);
    }
    asm volatile("s_waitcnt vmcnt(0)" ::: "memory");
    __syncthreads();  // slice resident for all waves

    // ---- 8 barrier-free 32-k sub-steps ----
    const float* Aw = A0 + wave * 4096 + lr * 256;
#pragma unroll
    for (int st = 0; st < 8; ++st) {
      const int c0 = (st << 3) + ((2 * lk) ^ (lr & 7));
      const int c1 = (st << 3) + ((2 * lk + 1) ^ (lr & 7));
      const float4 f0 = *reinterpret_cast<const float4*>(Aw + (c0 << 2));
      const float4 f1 = *reinterpret_cast<const float4*>(Aw + (c1 << 2));
      bf16x8 Ahi, Alo;
      split8(f0, f1, Ahi, Alo);
      const __bf16* bhp = BH + st * 2048 + lane * 8;
      const __bf16* blp = BL + st * 2048 + lane * 8;
      bf16x8 BHf[4], BLf[4];
#pragma unroll
      for (int j = 0; j < 4; ++j) {
        BHf[j] = *reinterpret_cast<const bf16x8*>(bhp + j * 512);
        BLf[j] = *reinterpret_cast<const bf16x8*>(blp + j * 512);
      }
      // term-major; per-acc order LL, LH, HL, HH (identical to R10-R18)
#pragma unroll
      for (int j = 0; j < 4; ++j)
        acc[j] = __builtin_amdgcn_mfma_f32_16x16x32_bf16(Alo, BLf[j], acc[j], 0, 0, 0);
#pragma unroll
      for (int j = 0; j < 4; ++j)
        acc[j] = __builtin_amdgcn_mfma_f32_16x16x32_bf16(Alo, BHf[j], acc[j], 0, 0, 0);
#pragma unroll
      for (int j = 0; j < 4; ++j)
        acc[j] = __builtin_amdgcn_mfma_f32_16x16x32_bf16(Ahi, BLf[j], acc[j], 0, 0, 0);
#pragma unroll
      for (int j = 0; j < 4; ++j)
        acc[j] = __builtin_amdgcn_mfma_f32_16x16x32_bf16(Ahi, BHf[j], acc[j], 0, 0, 0);
    }
  }

  // ---- epilogue: transpose scores to token-major LDS (aliases smem) ----
  __syncthreads();
  float* Ls = (float*)smem;  // 64*68*4 = 17408 B <= 131072
#pragma unroll
  for (int j = 0; j < 4; ++j)
#pragma unroll
    for (int r = 0; r < 4; ++r)
      Ls[(16 * wave + 4 * lk + r) * LSTR + 16 * j + lr] = acc[j][r];
  __syncthreads();

  const float bv = bias[lane];
  for (int tt = 0; tt < 16; ++tt) {
    const int tl = wave * 16 + tt;
    const int t = row0 + tl;
    const float s = Ls[tl * LSTR + lane] + bv;

    float m = s;
#pragma unroll
    for (int off = 32; off >= 1; off >>= 1) m = fmaxf(m, __shfl_xor(m, off));
    const float e = expf(s - m);
    float sum = e;
#pragma unroll
    for (int off = 32; off >= 1; off >>= 1) sum += __shfl_xor(sum, off);
    const float p = e / sum;

    // top-9 on biased raw score, lowest-index tie-break (matches lax.top_k)
    float wsel = s;
    float rv = 0.f;
    int ri = 0;
    float prev = 0.f, mingap = 1e30f;
#pragma unroll
    for (int r = 0; r < 9; ++r) {
      float v = wsel;
      int ii = lane;
#pragma unroll
      for (int off = 32; off >= 1; off >>= 1) {
        const float ov = __shfl_xor(v, off);
        const int oi = __shfl_xor(ii, off);
        if (ov > v || (ov == v && oi < ii)) { v = ov; ii = oi; }
      }
      if (r > 0) mingap = fminf(mingap, prev - v);
      prev = v;
      const float pw = __shfl(p, ii);
      if (lane == r) { rv = pw; ri = ii; }
      if (lane == ii) wsel = -1e30f;
    }

    bool toC = false;
    if (mingap < TAU && cap > 0) {
      int pos = 0;
      if (lane == 0) pos = atomicAdd(cnt, 1);
      pos = __shfl(pos, 0);
      if (pos < cap) {
        if (lane == 0) list[pos] = t;
        toC = true;  // recompute kernel produces all outputs for this token
      }
    }
    if (!toC) {
      S[(size_t)t * NE + lane] = p;
      if (lane < K) {
        wout[(size_t)t * K + lane] = rv;
        iout[(size_t)t * K + lane] = (float)ri;
        atomicAdd(&hist_s[ri], 1);
      }
    }
  }
  __syncthreads();
  if (tid < NE) atomicAdd(&hist[tid], hist_s[tid]);
}

// -------- f64 finalize for one token (lanes 0..63) ---------------
__device__ __forceinline__ void finalize_token_f64(
    int t, int lane, double s, float* __restrict__ S, float* __restrict__ wout,
    float* __restrict__ iout, int* __restrict__ hist, int K) {
  double m = s;
#pragma unroll
  for (int off = 32; off >= 1; off >>= 1) m = fmax(m, __shfl_xor(m, off));
  const double ex = exp(s - m);
  double sum = ex;
#pragma unroll
  for (int off = 32; off >= 1; off >>= 1) sum += __shfl_xor(sum, off);
  const double p = ex / sum;
  S[(size_t)t * NE + lane] = (float)p;
  double wsel = s;
  double rv = 0.0;
  int ri = 0;
  for (int r = 0; r < K; ++r) {
    double v = wsel;
    int ii = lane;
#pragma unroll
    for (int off = 32; off >= 1; off >>= 1) {
      const double ov = __shfl_xor(v, off);
      const int oi = __shfl_xor(ii, off);
      if (ov > v || (ov == v && oi < ii)) { v = ov; ii = oi; }
    }
    const double pw = __shfl(p, ii);
    if (lane == r) { rv = pw; ri = ii; }
    if (lane == ii) wsel = -1e300;
  }
  if (lane < K) {
    wout[(size_t)t * K + lane] = (float)rv;
    iout[(size_t)t * K + lane] = (float)ri;
    atomicAdd(&hist[ri], 1);
  }
}

// ------- Kernel 2: f64 recompute, 1 token/block, grid 512 -------------------
__global__ __launch_bounds__(256) void recompute_f64(
    const float* __restrict__ X, const float* __restrict__ W,
    const float* __restrict__ bias, float* __restrict__ S,
    float* __restrict__ wout, float* __restrict__ iout,
    const int* __restrict__ cnt, const int* __restrict__ list,
    int* __restrict__ hist, int H, int K, int cap) {
  if (cap <= 0) return;
  __shared__ float4 xs[1024];  // one token row (16 KB)
  __shared__ double red[256];
  const int tid = threadIdx.x;
  const int n = min(*cnt, cap);
  const int H4 = H >> 2;
  for (int idx = blockIdx.x; idx < n; idx += gridDim.x) {
    const int t = list[idx];
    __syncthreads();  // xs reuse from previous iteration
    const float4* xg = reinterpret_cast<const float4*>(X + (size_t)t * H);
    for (int i = tid; i < H4; i += 256) xs[i] = xg[i];
    __syncthreads();
    const int e = tid & 63, sl = tid >> 6;
    const int seg = H4 >> 2;  // 256 float4 per slice
    const float4* wr =
        reinterpret_cast<const float4*>(W + (size_t)e * H) + (size_t)sl * seg;
    const float4* xr = &xs[sl * seg];
    double a0 = 0.0, a1 = 0.0;  // split accumulators (break f64 dep chain)
    for (int k = 0; k < seg; k += 2) {
      const float4 w0 = wr[k], w1 = wr[k + 1];
      const float4 v0 = xr[k], v1 = xr[k + 1];
      a0 = fma((double)v0.x, (double)w0.x, a0);
      a0 = fma((double)v0.y, (double)w0.y, a0);
      a0 = fma((double)v0.z, (double)w0.z, a0);
      a0 = fma((double)v0.w, (double)w0.w, a0);
      a1 = fma((double)v1.x, (double)w1.x, a1);
      a1 = fma((double)v1.y, (double)w1.y, a1);
      a1 = fma((double)v1.z, (double)w1.z, a1);
      a1 = fma((double)v1.w, (double)w1.w, a1);
    }
    red[tid] = a0 + a1;
    __syncthreads();
    if (tid < 64) {
      const double s =
          red[e] + red[64 + e] + red[128 + e] + red[192 + e] + (double)bias[e];
      finalize_token_f64(t, e, s, S, wout, iout, hist, K);
    }
  }
}

// ------------- Kernel 3: bias update from integer histogram -----------------
__global__ void bias_update(const int* __restrict__ hist,
                            const float* __restrict__ bias,
                            float* __restrict__ bout, float tpe) {
  const int e = threadIdx.x;
  const float d = (float)hist[e] - tpe;
  const float sg = (d > 0.f) ? 1.f : ((d < 0.f) ? -1.f : 0.f);
  bout[e] = bias[e] + 0.01f * sg;
}

extern "C" void kernel_launch(void* const* d_in, const int* in_sizes, int n_in,
                              void* d_out, int out_size, void* d_ws, size_t ws_size,
                              hipStream_t stream) {
  const float* x = (const float*)d_in[0];
  const float* w = (const float*)d_in[1];
  const float* bias = (const float*)d_in[2];
  const int E = in_sizes[2];                       // 64
  const int H = in_sizes[1] / E;                   // 4096
  const long long N = (long long)in_sizes[0] / H;  // 32768 tokens
  const int K = (int)(((long long)out_size - N * E - E) / (2 * N));  // 8

  float* S = (float*)d_out;            // [N][E] probs
  float* wout = S + (size_t)N * E;     // [N][K]
  float* iout = wout + (size_t)N * K;  // [N][K] indices as float
  float* bout = iout + (size_t)N * K;  // [E]

  // ws: [0,4) cnt | [256,512) hist | Whi @4KB (512KB) | Wlo | list after
  int* cnt = (int*)d_ws;
  int* hist = (int*)d_ws + 64;
  const size_t whalf = (size_t)E * H * sizeof(__bf16);  // 512 KB
  __bf16* Whi = (__bf16*)((char*)d_ws + 4096);
  __bf16* Wlo = (__bf16*)((char*)d_ws + 4096 + whalf);
  const size_t listoff = 4096 + 2 * whalf;
  int* list = (int*)((char*)d_ws + listoff);
  int cap = 0;
  if (ws_size > listoff + 65536)
    cap = (int)min((size_t)32768, (ws_size - listoff) / 4);

  zero512<<<dim3(1), dim3(128), 0, stream>>>((int*)d_ws);
  const int n8 = E * H / 8;
  wconvert<<<dim3((n8 + 255) / 256), 256, 0, stream>>>(w, Whi, Wlo, n8, H);
  gemm_fused<<<dim3((int)(N / 64)), 256, 0, stream>>>(
      x, Whi, Wlo, bias, S, wout, iout, cnt, hist, list, cap, H, K);
  recompute_f64<<<dim3(512), 256, 0, stream>>>(x, w, bias, S, wout, iout, cnt,
                                               list, hist, H, K, cap);
  bias_update<<<dim3(1), dim3(E), 0, stream>>>(hist, bias, bout,
                                               (float)((double)N * K / E));
}

// Round 20
// 303.961 us; speedup vs baseline: 1.3126x; 1.3126x over previous
//
#include <hip/hip_runtime.h>

#define NE 64
#define TAU 1e-4f  // 4-term split-bf16 score sigma ~5e-6 -> 20-sigma guard
#define LSTR 68    // 68 mod 32 = 4 -> 2-way (free) LDS access in epilogue

typedef __bf16 bf16x8 __attribute__((ext_vector_type(8)));
typedef float f32x4 __attribute__((ext_vector_type(4)));

// split f32 -> bf16 hi + bf16 lo (hi RNE, lo = RNE(x - hi); x-hi exact in f32)
__device__ __forceinline__ void split8(const float4 a0, const float4 a1,
                                       bf16x8& hi, bf16x8& lo) {
  const float xs[8] = {a0.x, a0.y, a0.z, a0.w, a1.x, a1.y, a1.z, a1.w};
#pragma unroll
  for (int i = 0; i < 8; ++i) {
    const __bf16 h = (__bf16)xs[i];
    hi[i] = h;
    lo[i] = (__bf16)(xs[i] - (float)h);
  }
}

// async global->LDS, 16B/lane; LDS dest = wave-uniform base, HW adds lane*16
__device__ __forceinline__ void gld16(const void* g, void* l) {
  __builtin_amdgcn_global_load_lds(
      (const __attribute__((address_space(1))) void*)g,
      (__attribute__((address_space(3))) void*)l, 16, 0, 0);
}

// ---- Kernel Z: zero cnt+hist ------------------------------------------------
__global__ void zero512(int* __restrict__ p) { p[threadIdx.x] = 0; }

// ---- Kernel 0: W -> bf16 hi/lo in FRAGMENT-MAJOR 32-k tiles (1 MB, once) ---
// elem(tt, j, lk, lr, kr) = tt*2048 + j*512 + (lk*16+lr)*8 + kr
// where W-row e = 16j+lr, k = 32tt + 8lk + kr. A 64-k slice s (tt in
// {2s,2s+1}) is 4096 contiguous elems (8 KB) -> linear DMA to LDS.
__global__ __launch_bounds__(256) void wconvert(const float* __restrict__ W,
                                                __bf16* __restrict__ Whi,
                                                __bf16* __restrict__ Wlo,
                                                int n8, int H) {
  const int i = blockIdx.x * 256 + threadIdx.x;
  if (i >= n8) return;
  const int hc = H >> 3;
  const int e = i / hc;
  const int k0 = (i - e * hc) * 8;
  const float4 a0 = *reinterpret_cast<const float4*>(W + (size_t)e * H + k0);
  const float4 a1 =
      *reinterpret_cast<const float4*>(W + (size_t)e * H + k0 + 4);
  bf16x8 hi, lo;
  split8(a0, a1, hi, lo);
  const int tt = k0 >> 5, lk = (k0 >> 3) & 3, j = e >> 4, lr = e & 15;
  const size_t off = (size_t)tt * 2048 + j * 512 + (lk * 16 + lr) * 8;
  *reinterpret_cast<bf16x8*>(Whi + off) = hi;
  *reinterpret_cast<bf16x8*>(Wlo + off) = lo;
}

// ------- Kernel 1: 8-wave 128-token GEMM, 64k slices, high TLP --------------
// 8 waves x 16 tokens = 128 tokens/block; grid N/128 = 256 blocks; 48 KB LDS
// -> 2-3 resident blocks/CU = 16-24 waves/CU (4-6/SIMD). Per 64-k slice per
// wave: 4 A gld16 (each 1 KB contiguous = 4 rows x 256B, 16B chunks
// half-group-XOR-preswizzled) + 2 B gld16 (fragment-major, 1 KB contiguous);
// vmcnt(0); barrier; 2 barrier-free 32-k sub-steps (2 A + 8 B ds_read_b128 +
// 16 MFMA 4-term split-bf16, order identical to R10-R19).
__global__ __launch_bounds__(512, 4) void gemm_fused(
    const float* __restrict__ X, const __bf16* __restrict__ Whi,
    const __bf16* __restrict__ Wlo, const float* __restrict__ bias,
    float* __restrict__ S, float* __restrict__ wout, float* __restrict__ iout,
    int* __restrict__ cnt, int* __restrict__ hist, int* __restrict__ list,
    int cap, int H, int K) {
  __shared__ alignas(16) char smem[49152];  // A 32K | BH 8K | BL 8K
  __shared__ int hist_s[NE];
  const int tid = threadIdx.x;
  const int lane = tid & 63;
  const int wave = tid >> 6;  // 0..7
  if (tid < NE) hist_s[tid] = 0;
  const int lr = lane & 15;
  const int lk = lane >> 4;
  const int row0 = blockIdx.x * 128;

  float* A0 = (float*)smem;              // [wave][16 rows][16 chunks ^ swz]
  __bf16* BH = (__bf16*)(smem + 32768);  // [2 st][4 j][64 lane][8]
  __bf16* BL = (__bf16*)(smem + 40960);

  // A sources: instr i (0..3) covers rows r = 4i + (lane>>4); phys chunk
  // p = lane&15 holds LOGICAL chunk (p&8) | ((p&7) ^ (r&7)) of the row's
  // 256B slice-run (16 chunks of 16B).
  const float* srcA[4];
#pragma unroll
  for (int i = 0; i < 4; ++i) {
    const int r = 4 * i + (lane >> 4);
    const int p = lane & 15;
    const int l = (p & 8) | ((p & 7) ^ (r & 7));
    srcA[i] = X + (size_t)(row0 + 16 * wave + r) * H + (l << 2);
  }
  const __bf16* srcBh = Whi + wave * 512 + lane * 8;
  const __bf16* srcBl = Wlo + wave * 512 + lane * 8;

  f32x4 acc[4] = {};
  const int NSL = H >> 6;  // 64 slices of 64 k

  for (int s = 0; s < NSL; ++s) {
    if (s) __syncthreads();  // all waves done reading previous slice
    // ---- stage slice s: A 4 KB/wave + B 2 KB/wave, all 1KB-contiguous ----
#pragma unroll
    for (int i = 0; i < 4; ++i)
      gld16(srcA[i] + s * 64, A0 + wave * 1024 + i * 256);
    gld16(srcBh + (size_t)s * 4096, BH + wave * 512);
    gld16(srcBl + (size_t)s * 4096, BL + wave * 512);
    asm volatile("s_waitcnt vmcnt(0)" ::: "memory");
    __syncthreads();  // slice resident for all waves

    // ---- 2 barrier-free 32-k sub-steps ----
    const float* Aw = A0 + wave * 1024 + lr * 64;
#pragma unroll
    for (int st = 0; st < 2; ++st) {
      const int p0 = (st << 3) + ((2 * lk) ^ (lr & 7));
      const int p1 = (st << 3) + ((2 * lk + 1) ^ (lr & 7));
      const float4 f0 = *reinterpret_cast<const float4*>(Aw + (p0 << 2));
      const float4 f1 = *reinterpret_cast<const float4*>(Aw + (p1 << 2));
      bf16x8 Ahi, Alo;
      split8(f0, f1, Ahi, Alo);
      const __bf16* bhp = BH + st * 2048 + lane * 8;
      const __bf16* blp = BL + st * 2048 + lane * 8;
      bf16x8 BHf[4], BLf[4];
#pragma unroll
      for (int j = 0; j < 4; ++j) {
        BHf[j] = *reinterpret_cast<const bf16x8*>(bhp + j * 512);
        BLf[j] = *reinterpret_cast<const bf16x8*>(blp + j * 512);
      }
      // term-major; per-acc order LL, LH, HL, HH (identical to R10-R19)
#pragma unroll
      for (int j = 0; j < 4; ++j)
        acc[j] = __builtin_amdgcn_mfma_f32_16x16x32_bf16(Alo, BLf[j], acc[j], 0, 0, 0);
#pragma unroll
      for (int j = 0; j < 4; ++j)
        acc[j] = __builtin_amdgcn_mfma_f32_16x16x32_bf16(Alo, BHf[j], acc[j], 0, 0, 0);
#pragma unroll
      for (int j = 0; j < 4; ++j)
        acc[j] = __builtin_amdgcn_mfma_f32_16x16x32_bf16(Ahi, BLf[j], acc[j], 0, 0, 0);
#pragma unroll
      for (int j = 0; j < 4; ++j)
        acc[j] = __builtin_amdgcn_mfma_f32_16x16x32_bf16(Ahi, BHf[j], acc[j], 0, 0, 0);
    }
  }

  // ---- epilogue: transpose scores to token-major LDS (aliases smem) ----
  __syncthreads();
  float* Ls = (float*)smem;  // 128*68*4 = 34816 B <= 49152
#pragma unroll
  for (int j = 0; j < 4; ++j)
#pragma unroll
    for (int r = 0; r < 4; ++r)
      Ls[(16 * wave + 4 * lk + r) * LSTR + 16 * j + lr] = acc[j][r];
  __syncthreads();

  const float bv = bias[lane];
  for (int tt = 0; tt < 16; ++tt) {
    const int tl = wave * 16 + tt;
    const int t = row0 + tl;
    const float s = Ls[tl * LSTR + lane] + bv;

    float m = s;
#pragma unroll
    for (int off = 32; off >= 1; off >>= 1) m = fmaxf(m, __shfl_xor(m, off));
    const float e = expf(s - m);
    float sum = e;
#pragma unroll
    for (int off = 32; off >= 1; off >>= 1) sum += __shfl_xor(sum, off);
    const float p = e / sum;

    // top-9 on biased raw score, lowest-index tie-break (matches lax.top_k)
    float wsel = s;
    float rv = 0.f;
    int ri = 0;
    float prev = 0.f, mingap = 1e30f;
#pragma unroll
    for (int r = 0; r < 9; ++r) {
      float v = wsel;
      int ii = lane;
#pragma unroll
      for (int off = 32; off >= 1; off >>= 1) {
        const float ov = __shfl_xor(v, off);
        const int oi = __shfl_xor(ii, off);
        if (ov > v || (ov == v && oi < ii)) { v = ov; ii = oi; }
      }
      if (r > 0) mingap = fminf(mingap, prev - v);
      prev = v;
      const float pw = __shfl(p, ii);
      if (lane == r) { rv = pw; ri = ii; }
      if (lane == ii) wsel = -1e30f;
    }

    bool toC = false;
    if (mingap < TAU && cap > 0) {
      int pos = 0;
      if (lane == 0) pos = atomicAdd(cnt, 1);
      pos = __shfl(pos, 0);
      if (pos < cap) {
        if (lane == 0) list[pos] = t;
        toC = true;  // recompute kernel produces all outputs for this token
      }
    }
    if (!toC) {
      S[(size_t)t * NE + lane] = p;
      if (lane < K) {
        wout[(size_t)t * K + lane] = rv;
        iout[(size_t)t * K + lane] = (float)ri;
        atomicAdd(&hist_s[ri], 1);
      }
    }
  }
  __syncthreads();
  if (tid < NE) atomicAdd(&hist[tid], hist_s[tid]);
}

// -------- f64 finalize for one token (lanes 0..63) ---------------
__device__ __forceinline__ void finalize_token_f64(
    int t, int lane, double s, float* __restrict__ S, float* __restrict__ wout,
    float* __restrict__ iout, int* __restrict__ hist, int K) {
  double m = s;
#pragma unroll
  for (int off = 32; off >= 1; off >>= 1) m = fmax(m, __shfl_xor(m, off));
  const double ex = exp(s - m);
  double sum = ex;
#pragma unroll
  for (int off = 32; off >= 1; off >>= 1) sum += __shfl_xor(sum, off);
  const double p = ex / sum;
  S[(size_t)t * NE + lane] = (float)p;
  double wsel = s;
  double rv = 0.0;
  int ri = 0;
  for (int r = 0; r < K; ++r) {
    double v = wsel;
    int ii = lane;
#pragma unroll
    for (int off = 32; off >= 1; off >>= 1) {
      const double ov = __shfl_xor(v, off);
      const int oi = __shfl_xor(ii, off);
      if (ov > v || (ov == v && oi < ii)) { v = ov; ii = oi; }
    }
    const double pw = __shfl(p, ii);
    if (lane == r) { rv = pw; ri = ii; }
    if (lane == ii) wsel = -1e300;
  }
  if (lane < K) {
    wout[(size_t)t * K + lane] = (float)rv;
    iout[(size_t)t * K + lane] = (float)ri;
    atomicAdd(&hist[ri], 1);
  }
}

// ------- Kernel 2: f64 recompute, 1 token/block, grid 512 -------------------
__global__ __launch_bounds__(256) void recompute_f64(
    const float* __restrict__ X, const float* __restrict__ W,
    const float* __restrict__ bias, float* __restrict__ S,
    float* __restrict__ wout, float* __restrict__ iout,
    const int* __restrict__ cnt, const int* __restrict__ list,
    int* __restrict__ hist, int H, int K, int cap) {
  if (cap <= 0) return;
  __shared__ float4 xs[1024];  // one token row (16 KB)
  __shared__ double red[256];
  const int tid = threadIdx.x;
  const int n = min(*cnt, cap);
  const int H4 = H >> 2;
  for (int idx = blockIdx.x; idx < n; idx += gridDim.x) {
    const int t = list[idx];
    __syncthreads();  // xs reuse from previous iteration
    const float4* xg = reinterpret_cast<const float4*>(X + (size_t)t * H);
    for (int i = tid; i < H4; i += 256) xs[i] = xg[i];
    __syncthreads();
    const int e = tid & 63, sl = tid >> 6;
    const int seg = H4 >> 2;  // 256 float4 per slice
    const float4* wr =
        reinterpret_cast<const float4*>(W + (size_t)e * H) + (size_t)sl * seg;
    const float4* xr = &xs[sl * seg];
    double a0 = 0.0, a1 = 0.0;  // split accumulators (break f64 dep chain)
    for (int k = 0; k < seg; k += 2) {
      const float4 w0 = wr[k], w1 = wr[k + 1];
      const float4 v0 = xr[k], v1 = xr[k + 1];
      a0 = fma((double)v0.x, (double)w0.x, a0);
      a0 = fma((double)v0.y, (double)w0.y, a0);
      a0 = fma((double)v0.z, (double)w0.z, a0);
      a0 = fma((double)v0.w, (double)w0.w, a0);
      a1 = fma((double)v1.x, (double)w1.x, a1);
      a1 = fma((double)v1.y, (double)w1.y, a1);
      a1 = fma((double)v1.z, (double)w1.z, a1);
      a1 = fma((double)v1.w, (double)w1.w, a1);
    }
    red[tid] = a0 + a1;
    __syncthreads();
    if (tid < 64) {
      const double s =
          red[e] + red[64 + e] + red[128 + e] + red[192 + e] + (double)bias[e];
      finalize_token_f64(t, e, s, S, wout, iout, hist, K);
    }
  }
}

// ------------- Kernel 3: bias update from integer histogram -----------------
__global__ void bias_update(const int* __restrict__ hist,
                            const float* __restrict__ bias,
                            float* __restrict__ bout, float tpe) {
  const int e = threadIdx.x;
  const float d = (float)hist[e] - tpe;
  const float sg = (d > 0.f) ? 1.f : ((d < 0.f) ? -1.f : 0.f);
  bout[e] = bias[e] + 0.01f * sg;
}

extern "C" void kernel_launch(void* const* d_in, const int* in_sizes, int n_in,
                              void* d_out, int out_size, void* d_ws, size_t ws_size,
                              hipStream_t stream) {
  const float* x = (const float*)d_in[0];
  const float* w = (const float*)d_in[1];
  const float* bias = (const float*)d_in[2];
  const int E = in_sizes[2];                       // 64
  const int H = in_sizes[1] / E;                   // 4096
  const long long N = (long long)in_sizes[0] / H;  // 32768 tokens
  const int K = (int)(((long long)out_size - N * E - E) / (2 * N));  // 8

  float* S = (float*)d_out;            // [N][E] probs
  float* wout = S + (size_t)N * E;     // [N][K]
  float* iout = wout + (size_t)N * K;  // [N][K] indices as float
  float* bout = iout + (size_t)N * K;  // [E]

  // ws: [0,4) cnt | [256,512) hist | Whi @4KB (512KB) | Wlo | list after
  int* cnt = (int*)d_ws;
  int* hist = (int*)d_ws + 64;
  const size_t whalf = (size_t)E * H * sizeof(__bf16);  // 512 KB
  __bf16* Whi = (__bf16*)((char*)d_ws + 4096);
  __bf16* Wlo = (__bf16*)((char*)d_ws + 4096 + whalf);
  const size_t listoff = 4096 + 2 * whalf;
  int* list = (int*)((char*)d_ws + listoff);
  int cap = 0;
  if (ws_size > listoff + 65536)
    cap = (int)min((size_t)32768, (ws_size - listoff) / 4);

  zero512<<<dim3(1), dim3(128), 0, stream>>>((int*)d_ws);
  const int n8 = E * H / 8;
  wconvert<<<dim3((n8 + 255) / 256), 256, 0, stream>>>(w, Whi, Wlo, n8, H);
  gemm_fused<<<dim3((int)(N / 128)), 512, 0, stream>>>(
      x, Whi, Wlo, bias, S, wout, iout, cnt, hist, list, cap, H, K);
  recompute_f64<<<dim3(512), 256, 0, stream>>>(x, w, bias, S, wout, iout, cnt,
                                               list, hist, H, K, cap);
  bias_update<<<dim3(1), dim3(E), 0, stream>>>(hist, bias, bout,
                                               (float)((double)N * K / E));
}

// Round 21
// 262.056 us; speedup vs baseline: 1.5226x; 1.1599x over previous
//
#include <hip/hip_runtime.h>

#define NE 64
#define TAU 1e-4f  // 4-term split-bf16 score sigma ~5e-6 -> 20-sigma guard
#define LSTR 68    // 68 mod 32 = 4 -> 2-way (free) LDS access in epilogue

typedef __bf16 bf16x8 __attribute__((ext_vector_type(8)));
typedef float f32x4 __attribute__((ext_vector_type(4)));

// split f32 -> bf16 hi + bf16 lo (hi RNE, lo = RNE(x - hi); x-hi exact in f32)
__device__ __forceinline__ void split8(const float4 a0, const float4 a1,
                                       bf16x8& hi, bf16x8& lo) {
  const float xs[8] = {a0.x, a0.y, a0.z, a0.w, a1.x, a1.y, a1.z, a1.w};
#pragma unroll
  for (int i = 0; i < 8; ++i) {
    const __bf16 h = (__bf16)xs[i];
    hi[i] = h;
    lo[i] = (__bf16)(xs[i] - (float)h);
  }
}

// async global->LDS, 16B/lane; LDS dest = wave-uniform base, HW adds lane*16
__device__ __forceinline__ void gld16(const void* g, void* l) {
  __builtin_amdgcn_global_load_lds(
      (const __attribute__((address_space(1))) void*)g,
      (__attribute__((address_space(3))) void*)l, 16, 0, 0);
}

// ---- Kernel Z: zero cnt+hist ------------------------------------------------
__global__ void zero512(int* __restrict__ p) { p[threadIdx.x] = 0; }

// ---- Kernel 0: W -> bf16 hi/lo in FRAGMENT-MAJOR 32-k tiles (1 MB, once) ---
// elem(tt, j, lk, lr, kr) = tt*2048 + j*512 + (lk*16+lr)*8 + kr
// where W-row e = 16j+lr, k = 32tt + 8lk + kr.
__global__ __launch_bounds__(256) void wconvert(const float* __restrict__ W,
                                                __bf16* __restrict__ Whi,
                                                __bf16* __restrict__ Wlo,
                                                int n8, int H) {
  const int i = blockIdx.x * 256 + threadIdx.x;
  if (i >= n8) return;
  const int hc = H >> 3;
  const int e = i / hc;
  const int k0 = (i - e * hc) * 8;
  const float4 a0 = *reinterpret_cast<const float4*>(W + (size_t)e * H + k0);
  const float4 a1 =
      *reinterpret_cast<const float4*>(W + (size_t)e * H + k0 + 4);
  bf16x8 hi, lo;
  split8(a0, a1, hi, lo);
  const int tt = k0 >> 5, lk = (k0 >> 3) & 3, j = e >> 4, lr = e & 15;
  const size_t off = (size_t)tt * 2048 + j * 512 + (lk * 16 + lr) * 8;
  *reinterpret_cast<bf16x8*>(Whi + off) = hi;
  *reinterpret_cast<bf16x8*>(Wlo + off) = lo;
}

// ------- Kernel 1: row-contiguous-A GEMM, 2 blocks/CU phase overlap ---------
// 4 waves x 16 tokens = 64 tokens/block; grid N/64 = 512 = 2 blocks/CU.
// While one block drains its slice stage, the co-resident block computes
// (m114 wave-level overlap) -- no compiler pipelining needed.
// Per 128-k slice: A staged as 16 rows x 512B contiguous runs per wave
// (8 gld16, 16B chunks XOR-preswizzled within the run); B fragment-major
// (8 gld16/wave). Then 4 barrier-free 32-k steps: 2 A + 8 B ds_read_b128
// + 16 MFMA (4-term split-bf16; order identical to R10-R17).
__global__ __launch_bounds__(256, 2) void gemm_fused(
    const float* __restrict__ X, const __bf16* __restrict__ Whi,
    const __bf16* __restrict__ Wlo, const float* __restrict__ bias,
    float* __restrict__ S, float* __restrict__ wout, float* __restrict__ iout,
    int* __restrict__ cnt, int* __restrict__ hist, int* __restrict__ list,
    int cap, int H, int K) {
  __shared__ alignas(16) char smem[65536];  // A 32K | BH 16K | BL 16K
  __shared__ int hist_s[NE];
  const int tid = threadIdx.x;
  const int lane = tid & 63;
  const int wave = tid >> 6;  // 0..3
  if (tid < NE) hist_s[tid] = 0;
  const int lr = lane & 15;
  const int lk = lane >> 4;
  const int row0 = blockIdx.x * 64;

  float* A0 = (float*)smem;              // [wave][16 rows][32 chunks ^ swz]
  __bf16* BH = (__bf16*)(smem + 32768);  // [4 ts][4 j][64 lane][8]
  __bf16* BL = (__bf16*)(smem + 49152);

  // A staging sources: instr i, lane -> row r = 2i + (lane>>5), chunk slot
  // jj = lane&31 holds global chunk jj ^ (r&7) of this row's 512B slice-run.
  const int jj = lane & 31;
  const int half = lane >> 5;
  const float* srcA[8];
#pragma unroll
  for (int i = 0; i < 8; ++i) {
    const int r = 2 * i + half;
    srcA[i] = X + (size_t)(row0 + 16 * wave + r) * H + ((jj ^ (r & 7)) << 2);
  }
  // B staging: per slice, wave w stages tt-block w (2048 elems = 4 gld16 each
  // of hi and lo).
  const __bf16* srcBh = Whi + wave * 2048 + lane * 8;
  const __bf16* srcBl = Wlo + wave * 2048 + lane * 8;

  f32x4 acc[4] = {};
  const int NSL = H >> 7;  // 32 slices of 128 k

  for (int s = 0; s < NSL; ++s) {
    if (s) __syncthreads();  // all waves done reading previous slice
    // ---- stage A (8 gld16) + B (8 gld16) for slice s ----
#pragma unroll
    for (int i = 0; i < 8; ++i)
      gld16(srcA[i] + s * 128, A0 + wave * 2048 + i * 256);
#pragma unroll
    for (int i = 0; i < 4; ++i) {
      gld16(srcBh + (size_t)s * 8192 + i * 512, BH + wave * 2048 + i * 512);
      gld16(srcBl + (size_t)s * 8192 + i * 512, BL + wave * 2048 + i * 512);
    }
    asm volatile("s_waitcnt vmcnt(0)" ::: "memory");
    __syncthreads();  // slice resident for all waves

    // ---- 4 barrier-free 32-k steps ----
    const float* Aw = A0 + wave * 2048 + lr * 128;
#pragma unroll
    for (int ts = 0; ts < 4; ++ts) {
      const int c0 = (ts << 3) | (lk << 1);
      const float4 f0 =
          *reinterpret_cast<const float4*>(Aw + ((c0 ^ (lr & 7)) << 2));
      const float4 f1 =
          *reinterpret_cast<const float4*>(Aw + (((c0 + 1) ^ (lr & 7)) << 2));
      bf16x8 Ahi, Alo;
      split8(f0, f1, Ahi, Alo);
      const __bf16* bhp = BH + ts * 2048 + lane * 8;
      const __bf16* blp = BL + ts * 2048 + lane * 8;
      bf16x8 BHf[4], BLf[4];
#pragma unroll
      for (int j = 0; j < 4; ++j) {
        BHf[j] = *reinterpret_cast<const bf16x8*>(bhp + j * 512);
        BLf[j] = *reinterpret_cast<const bf16x8*>(blp + j * 512);
      }
      // term-major; per-acc order LL, LH, HL, HH (identical to R10-R17)
#pragma unroll
      for (int j = 0; j < 4; ++j)
        acc[j] = __builtin_amdgcn_mfma_f32_16x16x32_bf16(Alo, BLf[j], acc[j], 0, 0, 0);
#pragma unroll
      for (int j = 0; j < 4; ++j)
        acc[j] = __builtin_amdgcn_mfma_f32_16x16x32_bf16(Alo, BHf[j], acc[j], 0, 0, 0);
#pragma unroll
      for (int j = 0; j < 4; ++j)
        acc[j] = __builtin_amdgcn_mfma_f32_16x16x32_bf16(Ahi, BLf[j], acc[j], 0, 0, 0);
#pragma unroll
      for (int j = 0; j < 4; ++j)
        acc[j] = __builtin_amdgcn_mfma_f32_16x16x32_bf16(Ahi, BHf[j], acc[j], 0, 0, 0);
    }
  }

  // ---- epilogue: transpose scores to token-major LDS (aliases smem) ----
  __syncthreads();
  float* Ls = (float*)smem;  // 64*68*4 = 17408 B <= 65536
#pragma unroll
  for (int j = 0; j < 4; ++j)
#pragma unroll
    for (int r = 0; r < 4; ++r)
      Ls[(16 * wave + 4 * lk + r) * LSTR + 16 * j + lr] = acc[j][r];
  __syncthreads();

  const float bv = bias[lane];
  for (int tt = 0; tt < 16; ++tt) {
    const int tl = wave * 16 + tt;
    const int t = row0 + tl;
    const float s = Ls[tl * LSTR + lane] + bv;

    float m = s;
#pragma unroll
    for (int off = 32; off >= 1; off >>= 1) m = fmaxf(m, __shfl_xor(m, off));
    const float e = expf(s - m);
    float sum = e;
#pragma unroll
    for (int off = 32; off >= 1; off >>= 1) sum += __shfl_xor(sum, off);
    const float p = e / sum;

    // top-9 on biased raw score, lowest-index tie-break (matches lax.top_k)
    float wsel = s;
    float rv = 0.f;
    int ri = 0;
    float prev = 0.f, mingap = 1e30f;
#pragma unroll
    for (int r = 0; r < 9; ++r) {
      float v = wsel;
      int ii = lane;
#pragma unroll
      for (int off = 32; off >= 1; off >>= 1) {
        const float ov = __shfl_xor(v, off);
        const int oi = __shfl_xor(ii, off);
        if (ov > v || (ov == v && oi < ii)) { v = ov; ii = oi; }
      }
      if (r > 0) mingap = fminf(mingap, prev - v);
      prev = v;
      const float pw = __shfl(p, ii);
      if (lane == r) { rv = pw; ri = ii; }
      if (lane == ii) wsel = -1e30f;
    }

    bool toC = false;
    if (mingap < TAU && cap > 0) {
      int pos = 0;
      if (lane == 0) pos = atomicAdd(cnt, 1);
      pos = __shfl(pos, 0);
      if (pos < cap) {
        if (lane == 0) list[pos] = t;
        toC = true;  // recompute kernel produces all outputs for this token
      }
    }
    if (!toC) {
      S[(size_t)t * NE + lane] = p;
      if (lane < K) {
        wout[(size_t)t * K + lane] = rv;
        iout[(size_t)t * K + lane] = (float)ri;
        atomicAdd(&hist_s[ri], 1);
      }
    }
  }
  __syncthreads();
  if (tid < NE) atomicAdd(&hist[tid], hist_s[tid]);
}

// -------- f64 finalize for one token (lanes 0..63) ---------------
__device__ __forceinline__ void finalize_token_f64(
    int t, int lane, double s, float* __restrict__ S, float* __restrict__ wout,
    float* __restrict__ iout, int* __restrict__ hist, int K) {
  double m = s;
#pragma unroll
  for (int off = 32; off >= 1; off >>= 1) m = fmax(m, __shfl_xor(m, off));
  const double ex = exp(s - m);
  double sum = ex;
#pragma unroll
  for (int off = 32; off >= 1; off >>= 1) sum += __shfl_xor(sum, off);
  const double p = ex / sum;
  S[(size_t)t * NE + lane] = (float)p;
  double wsel = s;
  double rv = 0.0;
  int ri = 0;
  for (int r = 0; r < K; ++r) {
    double v = wsel;
    int ii = lane;
#pragma unroll
    for (int off = 32; off >= 1; off >>= 1) {
      const double ov = __shfl_xor(v, off);
      const int oi = __shfl_xor(ii, off);
      if (ov > v || (ov == v && oi < ii)) { v = ov; ii = oi; }
    }
    const double pw = __shfl(p, ii);
    if (lane == r) { rv = pw; ri = ii; }
    if (lane == ii) wsel = -1e300;
  }
  if (lane < K) {
    wout[(size_t)t * K + lane] = (float)rv;
    iout[(size_t)t * K + lane] = (float)ri;
    atomicAdd(&hist[ri], 1);
  }
}

// ------- Kernel 2: f64 recompute, 1 token/block, grid 512 -------------------
__global__ __launch_bounds__(256) void recompute_f64(
    const float* __restrict__ X, const float* __restrict__ W,
    const float* __restrict__ bias, float* __restrict__ S,
    float* __restrict__ wout, float* __restrict__ iout,
    const int* __restrict__ cnt, const int* __restrict__ list,
    int* __restrict__ hist, int H, int K, int cap) {
  if (cap <= 0) return;
  __shared__ float4 xs[1024];  // one token row (16 KB)
  __shared__ double red[256];
  const int tid = threadIdx.x;
  const int n = min(*cnt, cap);
  const int H4 = H >> 2;
  for (int idx = blockIdx.x; idx < n; idx += gridDim.x) {
    const int t = list[idx];
    __syncthreads();  // xs reuse from previous iteration
    const float4* xg = reinterpret_cast<const float4*>(X + (size_t)t * H);
    for (int i = tid; i < H4; i += 256) xs[i] = xg[i];
    __syncthreads();
    const int e = tid & 63, sl = tid >> 6;
    const int seg = H4 >> 2;  // 256 float4 per slice
    const float4* wr =
        reinterpret_cast<const float4*>(W + (size_t)e * H) + (size_t)sl * seg;
    const float4* xr = &xs[sl * seg];
    double a0 = 0.0, a1 = 0.0;  // split accumulators (break f64 dep chain)
    for (int k = 0; k < seg; k += 2) {
      const float4 w0 = wr[k], w1 = wr[k + 1];
      const float4 v0 = xr[k], v1 = xr[k + 1];
      a0 = fma((double)v0.x, (double)w0.x, a0);
      a0 = fma((double)v0.y, (double)w0.y, a0);
      a0 = fma((double)v0.z, (double)w0.z, a0);
      a0 = fma((double)v0.w, (double)w0.w, a0);
      a1 = fma((double)v1.x, (double)w1.x, a1);
      a1 = fma((double)v1.y, (double)w1.y, a1);
      a1 = fma((double)v1.z, (double)w1.z, a1);
      a1 = fma((double)v1.w, (double)w1.w, a1);
    }
    red[tid] = a0 + a1;
    __syncthreads();
    if (tid < 64) {
      const double s =
          red[e] + red[64 + e] + red[128 + e] + red[192 + e] + (double)bias[e];
      finalize_token_f64(t, e, s, S, wout, iout, hist, K);
    }
  }
}

// ------------- Kernel 3: bias update from integer histogram -----------------
__global__ void bias_update(const int* __restrict__ hist,
                            const float* __restrict__ bias,
                            float* __restrict__ bout, float tpe) {
  const int e = threadIdx.x;
  const float d = (float)hist[e] - tpe;
  const float sg = (d > 0.f) ? 1.f : ((d < 0.f) ? -1.f : 0.f);
  bout[e] = bias[e] + 0.01f * sg;
}

extern "C" void kernel_launch(void* const* d_in, const int* in_sizes, int n_in,
                              void* d_out, int out_size, void* d_ws, size_t ws_size,
                              hipStream_t stream) {
  const float* x = (const float*)d_in[0];
  const float* w = (const float*)d_in[1];
  const float* bias = (const float*)d_in[2];
  const int E = in_sizes[2];                       // 64
  const int H = in_sizes[1] / E;                   // 4096
  const long long N = (long long)in_sizes[0] / H;  // 32768 tokens
  const int K = (int)(((long long)out_size - N * E - E) / (2 * N));  // 8

  float* S = (float*)d_out;            // [N][E] probs
  float* wout = S + (size_t)N * E;     // [N][K]
  float* iout = wout + (size_t)N * K;  // [N][K] indices as float
  float* bout = iout + (size_t)N * K;  // [E]

  // ws: [0,4) cnt | [256,512) hist | Whi @4KB (512KB) | Wlo | list after
  int* cnt = (int*)d_ws;
  int* hist = (int*)d_ws + 64;
  const size_t whalf = (size_t)E * H * sizeof(__bf16);  // 512 KB
  __bf16* Whi = (__bf16*)((char*)d_ws + 4096);
  __bf16* Wlo = (__bf16*)((char*)d_ws + 4096 + whalf);
  const size_t listoff = 4096 + 2 * whalf;
  int* list = (int*)((char*)d_ws + listoff);
  int cap = 0;
  if (ws_size > listoff + 65536)
    cap = (int)min((size_t)32768, (ws_size - listoff) / 4);

  zero512<<<dim3(1), dim3(128), 0, stream>>>((int*)d_ws);
  const int n8 = E * H / 8;
  wconvert<<<dim3((n8 + 255) / 256), 256, 0, stream>>>(w, Whi, Wlo, n8, H);
  gemm_fused<<<dim3((int)(N / 64)), 256, 0, stream>>>(
      x, Whi, Wlo, bias, S, wout, iout, cnt, hist, list, cap, H, K);
  recompute_f64<<<dim3(512), 256, 0, stream>>>(x, w, bias, S, wout, iout, cnt,
                                               list, hist, H, K, cap);
  bias_update<<<dim3(1), dim3(E), 0, stream>>>(hist, bias, bout,
                                               (float)((double)N * K / E));
}